// Round 1
// baseline (276.764 us; speedup 1.0000x reference)
//
#include <hip/hip_runtime.h>
#include <stdint.h>

#define SEQ   2048
#define DIM   1024
#define BATCH 4

typedef _Float16 f16;
typedef __attribute__((ext_vector_type(8))) _Float16 f16x8;
typedef __attribute__((ext_vector_type(4))) _Float16 f16x4;
typedef __attribute__((ext_vector_type(4))) float   f32x4;

typedef void __attribute__((address_space(1))) vg_t;
typedef void __attribute__((address_space(3))) vl_t;

__device__ __forceinline__ void gld16(const void* g, void* l) {
  // async global->LDS, 16B per lane; LDS dest semantics: wave-uniform base + lane*16
  __builtin_amdgcn_global_load_lds((vg_t*)g, (vl_t*)l, 16, 0, 0);
}

// ---------------------------------------------------------------------------
// fp32 -> fp16 elementwise convert (4 elems/thread, vectorized)
// ---------------------------------------------------------------------------
__global__ __launch_bounds__(256) void cvt_f32_f16(const float* __restrict__ in,
                                                   f16* __restrict__ out, int n) {
  int i = (blockIdx.x * 256 + threadIdx.x) * 4;
  if (i < n) {
    float4 v = *(const float4*)(in + i);
    f16x4 o = { (f16)v.x, (f16)v.y, (f16)v.z, (f16)v.w };
    *(f16x4*)(out + i) = o;
  }
}

// ---------------------------------------------------------------------------
// NT GEMM: C[m,n] = sum_k A[m,k]*B[n,k], fp16 inputs, fp32 accumulate.
// 128x128 tile, BK=64, 4 waves (2x2 of 64x64), 16x16x32 MFMA.
// MODE: 0 = fp32 row-major C, 1 = fp16 row-major C, 2 = fp16 TRANSPOSED C (C[n][m])
// CAUSAL: 0 = none, 1 = skip blocks fully above diagonal (scores), 2 = K-limit m0+128 (PV)
// XOR chunk swizzle: LDS chunk (row, j) holds global 16B-chunk (j ^ (row&7)).
// ---------------------------------------------------------------------------
template <int MODE, int CAUSAL>
__global__ __launch_bounds__(256) void gemm_bt(const f16* __restrict__ A, int lda, long aOffZ,
                                               const f16* __restrict__ B, int ldb, long bOffZ,
                                               void* __restrict__ Cv, int ldc, long cOffZ,
                                               int K) {
  __shared__ __align__(16) f16 lA[128 * 64];
  __shared__ __align__(16) f16 lB[128 * 64];

  const int tid  = threadIdx.x;
  const int wave = tid >> 6;
  const int lane = tid & 63;
  const int m0 = blockIdx.x * 128;
  const int n0 = blockIdx.y * 128;
  const int z  = blockIdx.z;

  if (CAUSAL == 1 && n0 >= m0 + 128) return;     // tile fully above causal diagonal
  const int Keff = (CAUSAL == 2) ? (m0 + 128) : K;

  const f16* Ab = A + (long)z * aOffZ + (long)m0 * lda;
  const f16* Bb = B + (long)z * bOffZ + (long)n0 * ldb;

  const int wm = (wave & 1) * 64;
  const int wn = (wave >> 1) * 64;

  f32x4 acc[4][4] = {};

  const int srow = lane >> 3;   // row within 8-row staging group
  const int sj   = lane & 7;    // 16B chunk index within row
  const int fr   = lane & 15;   // fragment row
  const int fq   = lane >> 4;   // fragment quad

  for (int kt = 0; kt < Keff; kt += 64) {
    __syncthreads();  // previous iteration's ds_reads done
#pragma unroll
    for (int j = 0; j < 4; ++j) {
      const int rgrp = j * 4 + wave;          // 8-row group, 0..15
      const int row  = rgrp * 8 + srow;       // 0..127
      const int gch  = sj ^ (row & 7);        // swizzled global chunk
      gld16(Ab + (long)row * lda + kt + gch * 8, (void*)(lA + rgrp * 512 + lane * 8));
      gld16(Bb + (long)row * ldb + kt + gch * 8, (void*)(lB + rgrp * 512 + lane * 8));
    }
    __syncthreads();  // compiler drains vmcnt before barrier -> staging visible

#pragma unroll
    for (int kk = 0; kk < 64; kk += 32) {
      f16x8 af[4], bf[4];
#pragma unroll
      for (int i = 0; i < 4; ++i) {
        const int arow = wm + i * 16 + fr;
        const int ach  = (kk / 8 + fq) ^ (arow & 7);
        af[i] = *(const f16x8*)(lA + arow * 64 + ach * 8);
        const int brow = wn + i * 16 + fr;
        const int bch  = (kk / 8 + fq) ^ (brow & 7);
        bf[i] = *(const f16x8*)(lB + brow * 64 + bch * 8);
      }
#pragma unroll
      for (int mi = 0; mi < 4; ++mi)
#pragma unroll
        for (int ni = 0; ni < 4; ++ni)
          acc[mi][ni] = __builtin_amdgcn_mfma_f32_16x16x32_f16(af[mi], bf[ni], acc[mi][ni], 0, 0, 0);
    }
  }

  // Epilogue. C/D layout: col = lane&15, row = (lane>>4)*4 + reg
#pragma unroll
  for (int mi = 0; mi < 4; ++mi) {
    const int row = m0 + wm + mi * 16 + fq * 4;
#pragma unroll
    for (int ni = 0; ni < 4; ++ni) {
      const int col = n0 + wn + ni * 16 + fr;
      if constexpr (MODE == 0) {
        float* C = (float*)Cv + (long)z * cOffZ;
#pragma unroll
        for (int r = 0; r < 4; ++r) C[(long)(row + r) * ldc + col] = acc[mi][ni][r];
      } else if constexpr (MODE == 1) {
        f16* C = (f16*)Cv + (long)z * cOffZ;
#pragma unroll
        for (int r = 0; r < 4; ++r) C[(long)(row + r) * ldc + col] = (f16)acc[mi][ni][r];
      } else {  // MODE 2: transposed store C[col][row..row+3], 8B vector
        f16* C = (f16*)Cv + (long)z * cOffZ;
        f16x4 o = { (f16)acc[mi][ni][0], (f16)acc[mi][ni][1],
                    (f16)acc[mi][ni][2], (f16)acc[mi][ni][3] };
        *(f16x4*)(C + (long)col * ldc + row) = o;
      }
    }
  }
}

// ---------------------------------------------------------------------------
// Causal softmax over score rows, in-place fp32 -> fp16 probs (zero-filled
// above diagonal). grid = (SEQ, BATCH), block = 256. scale = 1/sqrt(1024).
// ---------------------------------------------------------------------------
__global__ __launch_bounds__(256) void softmax_causal(float* S) {
  const int q = blockIdx.x, b = blockIdx.y;
  float* row = S + ((long)b * SEQ + q) * SEQ;
  f16* prow = (f16*)row;  // in-place: probs occupy first half of the 8KB row
  const int tid = threadIdx.x;
  const int lane = tid & 63, wave = tid >> 6;
  const int nvalid = q + 1;

  float v[8];
  float m = -3.0e38f;
#pragma unroll
  for (int i = 0; i < 8; ++i) {
    const int k = tid + i * 256;
    v[i] = (k < nvalid) ? row[k] * 0.03125f : -3.0e38f;
    m = fmaxf(m, v[i]);
  }
#pragma unroll
  for (int off = 32; off; off >>= 1) m = fmaxf(m, __shfl_xor(m, off));
  __shared__ float redm[4], reds[4];
  if (lane == 0) redm[wave] = m;
  __syncthreads();  // all fp32 reads complete before this point
  m = fmaxf(fmaxf(redm[0], redm[1]), fmaxf(redm[2], redm[3]));

  float s = 0.f;
#pragma unroll
  for (int i = 0; i < 8; ++i) {
    const float p = (v[i] > -1.0e37f) ? __expf(v[i] - m) : 0.f;
    v[i] = p;
    s += p;
  }
#pragma unroll
  for (int off = 32; off; off >>= 1) s += __shfl_xor(s, off);
  if (lane == 0) reds[wave] = s;
  __syncthreads();
  s = reds[0] + reds[1] + reds[2] + reds[3];
  const float inv = 1.f / s;
#pragma unroll
  for (int i = 0; i < 8; ++i) {
    const int k = tid + i * 256;
    prow[k] = (f16)(v[i] * inv);  // writes only after barriers -> no overlap hazard
  }
}

// ---------------------------------------------------------------------------
extern "C" void kernel_launch(void* const* d_in, const int* in_sizes, int n_in,
                              void* d_out, int out_size, void* d_ws, size_t ws_size,
                              hipStream_t stream) {
  const float* x  = (const float*)d_in[0];
  const float* Wq = (const float*)d_in[1];
  const float* Wk = (const float*)d_in[2];
  const float* Wv = (const float*)d_in[3];
  float* out = (float*)d_out;

  // workspace layout (needs 134 MB):
  //   xb  : 8M f16   | Wh: 3M f16 (Wq,Wk,Wv) | Qh: 8M | Kh: 8M | VT: 8M (as [1024][8192])
  //   Sc  : 16M f32 scores (4 x 2048 x 2048), probs written in-place as f16 (row stride 4096)
  if (ws_size < 140509184u) return;  // signal via stub-like failure if ws too small

  f16* xb = (f16*)d_ws;
  f16* Wh = xb + (size_t)8 * 1024 * 1024;
  f16* Qh = Wh + (size_t)3 * 1024 * 1024;
  f16* Kh = Qh + (size_t)8 * 1024 * 1024;
  f16* VT = Kh + (size_t)8 * 1024 * 1024;
  float* Sc = (float*)(VT + (size_t)8 * 1024 * 1024);

  const long QOFF = (long)SEQ * DIM;        // per-batch Q/K offset
  const long SOFF = (long)SEQ * SEQ;        // per-batch score offset (f32 elems)

  cvt_f32_f16<<<8192, 256, 0, stream>>>(x, xb, BATCH * SEQ * DIM);
  cvt_f32_f16<<<1024, 256, 0, stream>>>(Wq, Wh, DIM * DIM);
  cvt_f32_f16<<<1024, 256, 0, stream>>>(Wk, Wh + (size_t)DIM * DIM, DIM * DIM);
  cvt_f32_f16<<<1024, 256, 0, stream>>>(Wv, Wh + (size_t)2 * DIM * DIM, DIM * DIM);

  // QKV projections: M=8192, N=1024, K=1024 (NT). V stored transposed as VT[p][b*S+s].
  gemm_bt<1, 0><<<dim3(64, 8, 1), 256, 0, stream>>>(xb, DIM, 0, Wh, DIM, 0, Qh, DIM, 0, DIM);
  gemm_bt<1, 0><<<dim3(64, 8, 1), 256, 0, stream>>>(xb, DIM, 0, Wh + (size_t)DIM * DIM, DIM, 0, Kh, DIM, 0, DIM);
  gemm_bt<2, 0><<<dim3(64, 8, 1), 256, 0, stream>>>(xb, DIM, 0, Wh + (size_t)2 * DIM * DIM, DIM, 0, VT, BATCH * SEQ, 0, DIM);

  // scores = Q K^T (causal block-skip), fp32 out
  gemm_bt<0, 1><<<dim3(16, 16, 4), 256, 0, stream>>>(Qh, DIM, QOFF, Kh, DIM, QOFF, Sc, SEQ, SOFF, DIM);

  // causal softmax (scale 1/32), in-place fp16 probs, zero above diagonal
  softmax_causal<<<dim3(SEQ, BATCH), 256, 0, stream>>>(Sc);

  // Z = P V  (A = probs f16, row stride 4096 elems; B = VT, ldb = 8192; K-limit per M-tile)
  gemm_bt<0, 2><<<dim3(16, 8, 4), 256, 0, stream>>>((const f16*)Sc, 2 * SEQ, (long)SEQ * 2 * SEQ,
                                                    VT, BATCH * SEQ, SEQ,
                                                    out, DIM, (long)SEQ * DIM, SEQ);
}

// Round 2
// 244.442 us; speedup vs baseline: 1.1322x; 1.1322x over previous
//
#include <hip/hip_runtime.h>
#include <stdint.h>

#define SEQ   2048
#define DIM   1024
#define BATCH 4

typedef _Float16 f16;
typedef __attribute__((ext_vector_type(8))) _Float16 f16x8;
typedef __attribute__((ext_vector_type(4))) _Float16 f16x4;
typedef __attribute__((ext_vector_type(4))) float   f32x4;

typedef void __attribute__((address_space(1))) vg_t;
typedef void __attribute__((address_space(3))) vl_t;

__device__ __forceinline__ void gld16(const void* g, void* l) {
  // async global->LDS, 16B per lane; LDS dest = wave-uniform base + lane*16
  __builtin_amdgcn_global_load_lds((vg_t*)g, (vl_t*)l, 16, 0, 0);
}

// ---------------------------------------------------------------------------
// Fused fp32->fp16 convert of x, Wq, Wk, Wv in ONE dispatch.
// blocks [0,8192): x (8M elems); [8192,9216): Wq; [9216,10240): Wk; rest: Wv.
// ---------------------------------------------------------------------------
__global__ __launch_bounds__(256) void cvt_all(const float* __restrict__ x,
                                               const float* __restrict__ wq,
                                               const float* __restrict__ wk,
                                               const float* __restrict__ wv,
                                               f16* __restrict__ xb,
                                               f16* __restrict__ wh) {
  const int bx = blockIdx.x;
  const float* in; f16* out; int base;
  if (bx < 8192)       { in = x;  out = xb;             base = bx; }
  else if (bx < 9216)  { in = wq; out = wh;             base = bx - 8192; }
  else if (bx < 10240) { in = wk; out = wh + (1 << 20); base = bx - 9216; }
  else                 { in = wv; out = wh + (2 << 20); base = bx - 10240; }
  const long i = ((long)base * 256 + threadIdx.x) * 4;
  float4 v = *(const float4*)(in + i);
  f16x4 o = { (f16)v.x, (f16)v.y, (f16)v.z, (f16)v.w };
  *(f16x4*)(out + i) = o;
}

// ---------------------------------------------------------------------------
// NT GEMM: C[m,n] = sum_k A[m,k]*B[n,k], fp16 in, fp32 accumulate.
// 128x128 tile, 4 waves (2x2 of 64x64), 16x16x32 MFMA, BK template (64/128).
// MODE: 0 = fp32 row-major C
//       1 = fp16 row-major C
//       2 = fp16 transposed C (C[n][m])
//       3 = fused QKV epilogue: col<1024 -> Q row-major, <2048 -> K row-major,
//           else -> V transposed [p][B*S] (Cv = Qh base; Kh/VT at fixed offsets)
// CAUSAL: 0 none, 1 skip tiles fully above diagonal (scores), 2 K-limit m0+128 (PV)
// XOR chunk swizzle: LDS slot (row, j) holds global 16B chunk j ^ (row & (CH-1)).
// ---------------------------------------------------------------------------
template <int MODE, int CAUSAL, int BK>
__global__ __launch_bounds__(256) void gemm_bt(const f16* __restrict__ A, int lda, long aOffZ,
                                               const f16* __restrict__ B, int ldb, long bOffZ,
                                               void* __restrict__ Cv, int ldc, long cOffZ,
                                               int K) {
  constexpr int CH  = BK / 8;    // 16B chunks per row
  constexpr int RPL = 64 / CH;   // rows per wave-load (8 @BK64, 4 @BK128)
  constexpr int NL  = 32 / RPL;  // wave-loads per tile per wave (4 / 8)
  __shared__ __align__(16) f16 lA[128 * BK];
  __shared__ __align__(16) f16 lB[128 * BK];

  const int tid  = threadIdx.x;
  const int wave = tid >> 6;
  const int lane = tid & 63;
  const int m0 = blockIdx.x * 128;
  const int n0 = blockIdx.y * 128;
  const int z  = blockIdx.z;

  if (CAUSAL == 1 && n0 >= m0 + 128) return;
  const int Keff = (CAUSAL == 2) ? (m0 + 128) : K;

  const f16* Ab = A + (long)z * aOffZ + (long)m0 * lda;
  const f16* Bb = B + (long)z * bOffZ + (long)n0 * ldb;

  const int wm = (wave & 1) * 64;
  const int wn = (wave >> 1) * 64;

  f32x4 acc[4][4] = {};

  const int srow = lane / CH;
  const int sj   = lane % CH;
  const int fr   = lane & 15;
  const int fq   = lane >> 4;

  for (int kt = 0; kt < Keff; kt += BK) {
    __syncthreads();  // previous iteration's ds_reads done
#pragma unroll
    for (int j = 0; j < NL; ++j) {
      const int rgrp = j * 4 + wave;
      const int row  = rgrp * RPL + srow;
      const int gch  = sj ^ (row & (CH - 1));
      gld16(Ab + (long)row * lda + kt + gch * 8, (void*)(lA + rgrp * 512 + lane * 8));
      gld16(Bb + (long)row * ldb + kt + gch * 8, (void*)(lB + rgrp * 512 + lane * 8));
    }
    __syncthreads();  // vmcnt drained -> staging visible

#pragma unroll
    for (int kk = 0; kk < BK; kk += 32) {
      f16x8 af[4], bf[4];
#pragma unroll
      for (int i = 0; i < 4; ++i) {
        const int arow = wm + i * 16 + fr;
        const int ach  = (kk / 8 + fq) ^ (arow & (CH - 1));
        af[i] = *(const f16x8*)(lA + arow * BK + ach * 8);
        const int brow = wn + i * 16 + fr;
        const int bch  = (kk / 8 + fq) ^ (brow & (CH - 1));
        bf[i] = *(const f16x8*)(lB + brow * BK + bch * 8);
      }
#pragma unroll
      for (int mi = 0; mi < 4; ++mi)
#pragma unroll
        for (int ni = 0; ni < 4; ++ni)
          acc[mi][ni] = __builtin_amdgcn_mfma_f32_16x16x32_f16(af[mi], bf[ni], acc[mi][ni], 0, 0, 0);
    }
  }

  // Epilogue. C/D layout: col = lane&15, row = (lane>>4)*4 + reg
#pragma unroll
  for (int mi = 0; mi < 4; ++mi) {
    const int row = m0 + wm + mi * 16 + fq * 4;
#pragma unroll
    for (int ni = 0; ni < 4; ++ni) {
      const int col = n0 + wn + ni * 16 + fr;
      if constexpr (MODE == 0) {
        float* C = (float*)Cv + (long)z * cOffZ;
#pragma unroll
        for (int r = 0; r < 4; ++r) C[(long)(row + r) * ldc + col] = acc[mi][ni][r];
      } else if constexpr (MODE == 1) {
        f16* C = (f16*)Cv + (long)z * cOffZ;
#pragma unroll
        for (int r = 0; r < 4; ++r) C[(long)(row + r) * ldc + col] = (f16)acc[mi][ni][r];
      } else if constexpr (MODE == 2) {
        f16* C = (f16*)Cv + (long)z * cOffZ;
        f16x4 o = { (f16)acc[mi][ni][0], (f16)acc[mi][ni][1],
                    (f16)acc[mi][ni][2], (f16)acc[mi][ni][3] };
        *(f16x4*)(C + (long)col * ldc + row) = o;
      } else {  // MODE 3: fused QKV routing (wave-uniform: 128-tile never straddles 1024-boundaries)
        f16* Qh  = (f16*)Cv;
        f16* Kh  = Qh + (size_t)8 * 1024 * 1024;
        f16* VTb = Kh + (size_t)8 * 1024 * 1024;
        if (col < 1024) {
#pragma unroll
          for (int r = 0; r < 4; ++r) Qh[(long)(row + r) * DIM + col] = (f16)acc[mi][ni][r];
        } else if (col < 2048) {
#pragma unroll
          for (int r = 0; r < 4; ++r) Kh[(long)(row + r) * DIM + (col - 1024)] = (f16)acc[mi][ni][r];
        } else {
          f16x4 o = { (f16)acc[mi][ni][0], (f16)acc[mi][ni][1],
                      (f16)acc[mi][ni][2], (f16)acc[mi][ni][3] };
          *(f16x4*)(VTb + (long)(col - 2048) * (BATCH * SEQ) + row) = o;
        }
      }
    }
  }
}

// ---------------------------------------------------------------------------
// Causal softmax over f16 score rows, in-place (zero above diagonal).
// grid = (SEQ, BATCH), block = 256, 8 contiguous elems/thread (f16x8).
// ---------------------------------------------------------------------------
__global__ __launch_bounds__(256) void softmax_causal(f16* S) {
  const int q = blockIdx.x, b = blockIdx.y;
  f16* row = S + ((long)b * SEQ + q) * SEQ;
  const int tid = threadIdx.x;
  const int lane = tid & 63, wave = tid >> 6;
  const int nvalid = q + 1;

  f16x8 vv = *(const f16x8*)(row + tid * 8);
  float v[8];
  float m = -3.0e38f;
#pragma unroll
  for (int i = 0; i < 8; ++i) {
    const int k = tid * 8 + i;
    v[i] = (k < nvalid) ? (float)vv[i] * 0.03125f : -3.0e38f;
    m = fmaxf(m, v[i]);
  }
#pragma unroll
  for (int off = 32; off; off >>= 1) m = fmaxf(m, __shfl_xor(m, off));
  __shared__ float redm[4], reds[4];
  if (lane == 0) redm[wave] = m;
  __syncthreads();  // all reads of `row` complete before this point
  m = fmaxf(fmaxf(redm[0], redm[1]), fmaxf(redm[2], redm[3]));

  float s = 0.f;
#pragma unroll
  for (int i = 0; i < 8; ++i) {
    const float p = (v[i] > -1.0e37f) ? __expf(v[i] - m) : 0.f;
    v[i] = p;
    s += p;
  }
#pragma unroll
  for (int off = 32; off; off >>= 1) s += __shfl_xor(s, off);
  if (lane == 0) reds[wave] = s;
  __syncthreads();
  s = reds[0] + reds[1] + reds[2] + reds[3];
  const float inv = 1.f / s;
  f16x8 o;
#pragma unroll
  for (int i = 0; i < 8; ++i) o[i] = (f16)(v[i] * inv);
  *(f16x8*)(row + tid * 8) = o;  // after barriers -> no overlap hazard
}

// ---------------------------------------------------------------------------
extern "C" void kernel_launch(void* const* d_in, const int* in_sizes, int n_in,
                              void* d_out, int out_size, void* d_ws, size_t ws_size,
                              hipStream_t stream) {
  const float* x  = (const float*)d_in[0];
  const float* Wq = (const float*)d_in[1];
  const float* Wk = (const float*)d_in[2];
  const float* Wv = (const float*)d_in[3];
  float* out = (float*)d_out;

  // ws layout (f16 elems): xb 8M | Wh 3M | Qh 8M | Kh 8M | VT 8M ([1024][8192]) |
  //                        Sc 16M f16 scores->probs in place (4 x 2048 x 2048)
  if (ws_size < (size_t)51 * 1024 * 1024 * 2) return;

  f16* xb = (f16*)d_ws;
  f16* Wh = xb + (size_t)8 * 1024 * 1024;
  f16* Qh = Wh + (size_t)3 * 1024 * 1024;
  f16* Kh = Qh + (size_t)8 * 1024 * 1024;
  f16* VT = Kh + (size_t)8 * 1024 * 1024;
  f16* Sc = VT + (size_t)8 * 1024 * 1024;

  const long QOFF = (long)SEQ * DIM;  // per-batch Q/K offset
  const long SOFF = (long)SEQ * SEQ;  // per-batch score offset (f16 elems)

  cvt_all<<<11264, 256, 0, stream>>>(x, Wq, Wk, Wv, xb, Wh);

  // Fused QKV: M=8192, N=3072 (Wq|Wk|Wv concatenated in Wh), K=1024.
  // Epilogue writes Qh/Kh row-major f16 and VT transposed; BK=64 keeps 5 blocks/CU.
  gemm_bt<3, 0, 64><<<dim3(64, 24, 1), 256, 0, stream>>>(xb, DIM, 0, Wh, DIM, 0, Qh, 0, 0, DIM);

  // scores = Q K^T (causal block-skip), f16 out, BK=128 (8 barrier-drains instead of 16)
  gemm_bt<1, 1, 128><<<dim3(16, 16, 4), 256, 0, stream>>>(Qh, DIM, QOFF, Kh, DIM, QOFF,
                                                          Sc, SEQ, SOFF, DIM);

  // causal softmax (scale 1/32), in-place f16 probs, zero above diagonal
  softmax_causal<<<dim3(SEQ, BATCH), 256, 0, stream>>>(Sc);

  // Z = P V  (A = probs f16 ld 2048; B = VT ld 8192; per-M-tile K-limit), BK=128
  gemm_bt<0, 2, 128><<<dim3(16, 8, 4), 256, 0, stream>>>(Sc, SEQ, SOFF,
                                                         VT, BATCH * SEQ, SEQ,
                                                         out, DIM, (long)SEQ * DIM, SEQ);
}